// Round 2
// baseline (81.926 us; speedup 1.0000x reference)
//
#include <hip/hip_runtime.h>
#include <math.h>

#define SIZE 128
#define BATCH 64
#define STEEP 10.0f

// alpha = atan(STEEP*delta)/pi + 0.5, branchless minimax (deg-11 odd poly,
// 1/pi folded into coefficients; v_rcp range reduction for |t|>1).
// abs err ~1e-6 in alpha — threshold is 3.6e-2, current slack 9x.
__device__ __forceinline__ float alpha_from_delta(float delta) {
    const float C0 =  0.31830265f;   // 0.99997726/pi
    const float C1 = -0.10587730f;   // -0.33262347/pi
    const float C2 =  0.06160680f;   //  0.19354346/pi
    const float C3 = -0.03706173f;   // -0.11643287/pi
    const float C4 =  0.01676007f;   //  0.05265332/pi
    const float C5 = -0.00373098f;   // -0.01172120/pi
    float t   = STEEP * delta;
    float at  = fabsf(t);
    bool  inv = at > 1.0f;
    float z   = inv ? __builtin_amdgcn_rcpf(at) : at;
    float z2  = z * z;
    float q   = C5;
    q = fmaf(q, z2, C4);
    q = fmaf(q, z2, C3);
    q = fmaf(q, z2, C2);
    q = fmaf(q, z2, C1);
    q = fmaf(q, z2, C0);
    q = q * z;                       // ~atan(z)/pi
    float r = inv ? 0.5f - q : q;    // atan(|t|)/pi
    return (t >= 0.0f) ? (0.5f + r) : (0.5f - r);
}

// Kernel A: the serial part. One wave per batch evolves x and emits every
// layer's alphas to alpha_buf[batch][layer][64]. Also writes final x to out.
// Lane p owns (x[2p], x[2p+1]).
__global__ __launch_bounds__(64) void alpha_kernel(
    const float* __restrict__ vec, float* __restrict__ alpha_buf,
    float* __restrict__ out)
{
    const int lane  = threadIdx.x;          // pair index p
    const int batch = blockIdx.x;
    const int c0    = 2 * lane;

    const float2 xv = *reinterpret_cast<const float2*>(vec + batch * SIZE + c0);
    float xa = xv.x, xb = xv.y;

    float* __restrict__ ab = alpha_buf + batch * (SIZE * 64);
    const int  laneR = (lane < 63) ? lane + 1 : 63;
    const int  laneL = (lane > 0)  ? lane - 1 : 0;
    const bool hasR  = (lane < 63);
    const bool hasL  = (lane > 0);

    for (int layer = 0; layer < SIZE; layer += 2) {
        // even layer: pair (2p, 2p+1), lane-local
        const float ae = alpha_from_delta(xb - xa);
        ab[layer * 64 + lane] = ae;
        const float t  = ae * (xa - xb);
        const float na = xb + t;
        xb = xa - t;
        xa = na;
        // odd layer: pair (2p+1, 2p+2)
        const float xnext = __shfl(xa, laneR);
        const float ao    = alpha_from_delta(xnext - xb);
        ab[(layer + 1) * 64 + lane] = ao;           // lane 63: garbage, never read
        const float aoL   = __shfl(ao, laneL);
        const float xprev = __shfl(xb, laneL);
        const float nxb = xnext + ao  * (xb - xnext);
        const float nxa = xprev + aoL * (xa - xprev);
        xb = hasR ? nxb : xb;
        xa = hasL ? nxa : xa;
    }
    *reinterpret_cast<float2*>(out + batch * SIZE + c0) = make_float2(xa, xb);
}

// Kernel B: the parallel part. Thread owns 1 row x 8 contiguous columns of X
// in registers. Even pairs + 3/4 odd pairs are thread-local; 2 boundary
// shuffles per odd layer. Alphas read from alpha_buf (wave-coherent, L1-hot),
// double-buffered one layer-pair ahead.
__global__ __launch_bounds__(256) void evolve_kernel(
    const float* __restrict__ alpha_buf, float* __restrict__ out)
{
    const int tid     = threadIdx.x;
    const int lane    = tid & 63;
    const int wave    = tid >> 6;
    const int chunk   = lane & 15;          // cols 8*chunk .. 8*chunk+7
    const int row_sub = lane >> 4;          // 4 rows per wave
    const int batch   = blockIdx.x >> 3;
    const int rowgrp  = blockIdx.x & 7;
    const int row     = rowgrp * 16 + wave * 4 + row_sub;
    const int c8      = chunk * 8;

    float v[8];
#pragma unroll
    for (int j = 0; j < 8; ++j) v[j] = (row == c8 + j) ? 1.0f : 0.0f;

    const float* __restrict__ ab = alpha_buf + batch * (SIZE * 64);
    const int q4 = chunk * 4;                       // even-pair base index
    const int qm = (q4 > 0) ? q4 - 1 : 0;           // left-boundary odd pair (clamped)

    const bool hasR  = (chunk < 15);
    const bool hasL  = (chunk > 0);
    const int  laneR = hasR ? lane + 1 : lane;
    const int  laneL = hasL ? lane - 1 : lane;

    // preload layer-pair 0
    float4 ae = *reinterpret_cast<const float4*>(ab + 0 * 64 + q4);
    float4 ao = *reinterpret_cast<const float4*>(ab + 1 * 64 + q4);
    float  aL = ab[1 * 64 + qm];

    for (int L = 0; L < 64; ++L) {
        // prefetch next layer-pair (clamped reload on last iter, unused)
        const int nxt = (L < 63) ? (2 * L + 2) : (2 * L);
        const float4 ae_n = *reinterpret_cast<const float4*>(ab + nxt * 64 + q4);
        const float4 ao_n = *reinterpret_cast<const float4*>(ab + (nxt + 1) * 64 + q4);
        const float  aL_n = ab[(nxt + 1) * 64 + qm];

        // ---- even layer: pairs (v0,v1)(v2,v3)(v4,v5)(v6,v7) ----
        {
            float A, B, d;
            A = v[0]; B = v[1]; d = A - B; v[0] = fmaf(ae.x, d, B); v[1] = fmaf(-ae.x, d, A);
            A = v[2]; B = v[3]; d = A - B; v[2] = fmaf(ae.y, d, B); v[3] = fmaf(-ae.y, d, A);
            A = v[4]; B = v[5]; d = A - B; v[4] = fmaf(ae.z, d, B); v[5] = fmaf(-ae.z, d, A);
            A = v[6]; B = v[7]; d = A - B; v[6] = fmaf(ae.w, d, B); v[7] = fmaf(-ae.w, d, A);
        }
        // ---- odd layer ----
        // boundary values (post-even, pre-boundary-update; wave-synchronous)
        const float nb0 = __shfl(v[0], laneR);   // right neighbor's col c8+8
        const float pb7 = __shfl(v[7], laneL);   // left neighbor's col c8-1
        {   // internal pairs (v1,v2)(v3,v4)(v5,v6)
            float A, B, d;
            A = v[1]; B = v[2]; d = A - B; v[1] = fmaf(ao.x, d, B); v[2] = fmaf(-ao.x, d, A);
            A = v[3]; B = v[4]; d = A - B; v[3] = fmaf(ao.y, d, B); v[4] = fmaf(-ao.y, d, A);
            A = v[5]; B = v[6]; d = A - B; v[5] = fmaf(ao.z, d, B); v[6] = fmaf(-ao.z, d, A);
        }
        // right boundary pair (a = v7, b = nb0), alpha = ao.w: a' = b + a*(a-b)
        const float r = fmaf(ao.w, v[7] - nb0, nb0);
        // left boundary pair (a = pb7, b = v0), alpha = aL: b' = a + a*(b-a)
        const float l = fmaf(aL, v[0] - pb7, pb7);
        v[7] = hasR ? r : v[7];
        v[0] = hasL ? l : v[0];

        ae = ae_n; ao = ao_n; aL = aL_n;
    }

    // store: X is out[8192 ..], row-major [batch][128][128]
    float* __restrict__ X = out + BATCH * SIZE + (batch * SIZE + row) * SIZE + c8;
    *reinterpret_cast<float4*>(X)     = make_float4(v[0], v[1], v[2], v[3]);
    *reinterpret_cast<float4*>(X + 4) = make_float4(v[4], v[5], v[6], v[7]);
}

extern "C" void kernel_launch(void* const* d_in, const int* in_sizes, int n_in,
                              void* d_out, int out_size, void* d_ws, size_t ws_size,
                              hipStream_t stream) {
    const float* vec = (const float*)d_in[0];
    float* out = (float*)d_out;
    float* alpha_buf = (float*)d_ws;    // 64*128*64*4 = 2 MB
    (void)in_sizes; (void)n_in; (void)ws_size; (void)out_size;

    hipLaunchKernelGGL(alpha_kernel, dim3(BATCH), dim3(64), 0, stream,
                       vec, alpha_buf, out);
    hipLaunchKernelGGL(evolve_kernel, dim3(BATCH * 8), dim3(256), 0, stream,
                       alpha_buf, out);
}

// Round 3
// 70.495 us; speedup vs baseline: 1.1621x; 1.1621x over previous
//
#include <hip/hip_runtime.h>
#include <math.h>

#define SIZE 128
#define BATCH 64
#define STEEP 10.0f

// DPP lane move: CTRL 0x101=row_shl:1 (lane i <- i+1, within 16-lane rows),
// 0x111=row_shr:1 (lane i <- i-1), 0x130=wave_shl:1 (lane i <- i+1, whole wave),
// 0x138=wave_shr:1 (lane i <- i-1). Invalid lanes keep old value (masked anyway).
template<int CTRL>
__device__ __forceinline__ float dpp_mov(float x) {
    return __int_as_float(__builtin_amdgcn_update_dpp(
        __float_as_int(x), __float_as_int(x), CTRL, 0xf, 0xf, false));
}

// alpha = atan(STEEP*delta)/pi + 0.5, branchless minimax (deg-11 odd poly,
// 1/pi folded in; v_rcp range reduction). abs err ~1e-6 (validated: absmax
// 3.9e-3 vs 3.6e-2 threshold in R1/R2 with this same poly).
__device__ __forceinline__ float alpha_from_delta(float delta) {
    const float C0 =  0.31830265f;
    const float C1 = -0.10587730f;
    const float C2 =  0.06160680f;
    const float C3 = -0.03706173f;
    const float C4 =  0.01676007f;
    const float C5 = -0.00373098f;
    float t   = STEEP * delta;
    float at  = fabsf(t);
    bool  inv = at > 1.0f;
    float z   = inv ? __builtin_amdgcn_rcpf(at) : at;
    float z2  = z * z;
    float q   = C5;
    q = fmaf(q, z2, C4);
    q = fmaf(q, z2, C3);
    q = fmaf(q, z2, C2);
    q = fmaf(q, z2, C1);
    q = fmaf(q, z2, C0);
    q = q * z;
    float r = inv ? 0.5f - q : q;
    return (t >= 0.0f) ? (0.5f + r) : (0.5f - r);
}

// One block = (batch, 32-row group). 512 threads = 8 waves.
// Phase 1: wave 0 runs the serial alpha chain (lane p owns pair p), fills
//          alds[layer][pair] (32 KB), writes final x if rowgrp==0.
// Phase 2: thread owns 1 row x 8 contiguous cols of X in registers; alphas
//          from LDS; boundary exchange via DPP row_shl/shr (chunk edges ==
//          16-lane row edges, masked). No d_ws, no inter-kernel dependency.
__global__ __launch_bounds__(512) void soft_sort_fused(
    const float* __restrict__ vec, float* __restrict__ out)
{
    __shared__ float alds[SIZE * 64];   // [layer][pair]

    const int tid    = threadIdx.x;
    const int lane   = tid & 63;
    const int wave   = tid >> 6;
    const int batch  = blockIdx.x >> 2;
    const int rowgrp = blockIdx.x & 3;

    // ---------------- Phase 1: serial alpha chain (wave 0 only) ------------
    if (wave == 0) {
        const int c0 = 2 * lane;
        const float2 xv = *reinterpret_cast<const float2*>(vec + batch * SIZE + c0);
        float xa = xv.x, xb = xv.y;
        const bool hasR = (lane < 63);
        const bool hasL = (lane > 0);

        for (int layer = 0; layer < SIZE; layer += 2) {
            // even layer: pair (2p, 2p+1), lane-local
            const float ae = alpha_from_delta(xb - xa);
            alds[layer * 64 + lane] = ae;
            const float t  = ae * (xa - xb);
            const float na = xb + t;
            xb = xa - t;
            xa = na;
            // odd layer: pair (2p+1, 2p+2)
            const float xnext = dpp_mov<0x130>(xa);       // lane i <- i+1
            const float ao    = alpha_from_delta(xnext - xb);
            alds[(layer + 1) * 64 + lane] = ao;           // lane 63: garbage, never read
            const float aoL   = dpp_mov<0x138>(ao);       // lane i <- i-1
            const float xprev = dpp_mov<0x138>(xb);
            const float nxb = fmaf(ao,  xb - xnext, xnext);
            const float nxa = fmaf(aoL, xa - xprev, xprev);
            xb = hasR ? nxb : xb;
            xa = hasL ? nxa : xa;
        }
        if (rowgrp == 0)
            *reinterpret_cast<float2*>(out + batch * SIZE + c0) = make_float2(xa, xb);
    }
    __syncthreads();

    // ---------------- Phase 2: evolve X rows ------------------------------
    const int chunk   = lane & 15;          // cols 8*chunk .. 8*chunk+7
    const int row_sub = lane >> 4;          // 4 rows per wave
    const int row     = rowgrp * 32 + wave * 4 + row_sub;
    const int c8      = chunk * 8;
    const int q4      = chunk * 4;          // even-pair base index
    const int qm      = (q4 > 0) ? q4 - 1 : 0;
    const bool hasR   = (chunk < 15);
    const bool hasL   = (chunk > 0);

    float v[8];
#pragma unroll
    for (int j = 0; j < 8; ++j) v[j] = (row == c8 + j) ? 1.0f : 0.0f;

    for (int L = 0; L < 64; ++L) {
        const float4 ae = *reinterpret_cast<const float4*>(&alds[(2 * L) * 64 + q4]);
        const float4 ao = *reinterpret_cast<const float4*>(&alds[(2 * L + 1) * 64 + q4]);
        const float  aL = alds[(2 * L + 1) * 64 + qm];

        // even layer: pairs (v0,v1)(v2,v3)(v4,v5)(v6,v7)
        {
            float A, B, d;
            A = v[0]; B = v[1]; d = A - B; v[0] = fmaf(ae.x, d, B); v[1] = fmaf(-ae.x, d, A);
            A = v[2]; B = v[3]; d = A - B; v[2] = fmaf(ae.y, d, B); v[3] = fmaf(-ae.y, d, A);
            A = v[4]; B = v[5]; d = A - B; v[4] = fmaf(ae.z, d, B); v[5] = fmaf(-ae.z, d, A);
            A = v[6]; B = v[7]; d = A - B; v[6] = fmaf(ae.w, d, B); v[7] = fmaf(-ae.w, d, A);
        }
        // boundary values (post-even, pre-odd; lanes lockstep within wave)
        const float nb0 = dpp_mov<0x101>(v[0]);   // right neighbor's col c8+8
        const float pb7 = dpp_mov<0x111>(v[7]);   // left neighbor's col c8-1
        // odd layer: internal pairs (v1,v2)(v3,v4)(v5,v6)
        {
            float A, B, d;
            A = v[1]; B = v[2]; d = A - B; v[1] = fmaf(ao.x, d, B); v[2] = fmaf(-ao.x, d, A);
            A = v[3]; B = v[4]; d = A - B; v[3] = fmaf(ao.y, d, B); v[4] = fmaf(-ao.y, d, A);
            A = v[5]; B = v[6]; d = A - B; v[5] = fmaf(ao.z, d, B); v[6] = fmaf(-ao.z, d, A);
        }
        // right boundary pair (a=v7, b=nb0): a' = b + alpha*(a-b)
        const float r = fmaf(ao.w, v[7] - nb0, nb0);
        // left boundary pair (a=pb7, b=v0): b' = a + alpha*(b-a)
        const float l = fmaf(aL, v[0] - pb7, pb7);
        v[7] = hasR ? r : v[7];
        v[0] = hasL ? l : v[0];
    }

    // store: X is out[8192 ..], row-major [batch][128][128]
    float* __restrict__ X = out + BATCH * SIZE + (batch * SIZE + row) * SIZE + c8;
    *reinterpret_cast<float4*>(X)     = make_float4(v[0], v[1], v[2], v[3]);
    *reinterpret_cast<float4*>(X + 4) = make_float4(v[4], v[5], v[6], v[7]);
}

extern "C" void kernel_launch(void* const* d_in, const int* in_sizes, int n_in,
                              void* d_out, int out_size, void* d_ws, size_t ws_size,
                              hipStream_t stream) {
    const float* vec = (const float*)d_in[0];
    float* out = (float*)d_out;
    (void)in_sizes; (void)n_in; (void)d_ws; (void)ws_size; (void)out_size;

    hipLaunchKernelGGL(soft_sort_fused, dim3(BATCH * 4), dim3(512), 0, stream,
                       vec, out);
}

// Round 4
// 69.113 us; speedup vs baseline: 1.1854x; 1.0200x over previous
//
#include <hip/hip_runtime.h>
#include <math.h>

#define SIZE 128
#define BATCH 64
#define STEEP 10.0f
#define G 8      // layer-pairs per pipeline group
#define NG 8     // groups: 8*8 = 64 layer-pairs = 128 layers

// DPP lane move (verified passing in R3): 0x101=row_shl:1 (lane i <- i+1,
// 16-lane rows), 0x111=row_shr:1 (i <- i-1), 0x130=wave_shl:1 (i <- i+1),
// 0x138=wave_shr:1 (i <- i-1). bound_ctrl=false: invalid lanes keep old value.
template<int CTRL>
__device__ __forceinline__ float dpp_mov(float x) {
    return __int_as_float(__builtin_amdgcn_update_dpp(
        __float_as_int(x), __float_as_int(x), CTRL, 0xf, 0xf, false));
}

// alpha = atan(STEEP*delta)/pi + 0.5. Estrin-evaluated minimax poly (1/pi
// folded in), v_rcp range reduction, copysign sign-fold. err ~1e-6
// (absmax 3.9e-3 vs 3.6e-2 threshold with this poly, R1-R3).
__device__ __forceinline__ float alpha_from_delta(float delta) {
    const float C0 =  0.31830265f;
    const float C1 = -0.10587730f;
    const float C2 =  0.06160680f;
    const float C3 = -0.03706173f;
    const float C4 =  0.01676007f;
    const float C5 = -0.00373098f;
    float t  = STEEP * delta;
    float at = fabsf(t);
    bool inv = at > 1.0f;
    float z  = inv ? __builtin_amdgcn_rcpf(at) : at;
    float z2 = z * z, z4 = z2 * z2;
    float p0 = fmaf(C1, z2, C0);
    float p1 = fmaf(C3, z2, C2);
    float p2 = fmaf(C5, z2, C4);
    float q  = fmaf(fmaf(p2, z4, p1), z4, p0) * z;
    float r  = inv ? 0.5f - q : q;           // atan(|t|)/pi
    return 0.5f + copysignf(r, t);           // r >= 0 always
}

// One block = (batch, 32-row group). 576 threads = 9 waves.
// Wave 8 (producer): serial alpha chain, fills ping-pong LDS groups of G
//   layer-pairs; pads pair-63 of odd layers with alpha=1.0 (identity no-op).
// Waves 0-7 (consumers): 1 row x 8 contiguous cols of X in registers;
//   boundary exchange via DPP; zero predication (alpha=1 pad handles edges).
__global__ __launch_bounds__(576) void soft_sort_fused(
    const float* __restrict__ vec, float* __restrict__ out)
{
    __shared__ float alds[2][2 * G * 64];   // [buf][layer_in_group][pair]

    const int tid    = threadIdx.x;
    const int lane   = tid & 63;
    const int wave   = tid >> 6;
    const int batch  = blockIdx.x >> 2;
    const int rowgrp = blockIdx.x & 3;

    if (wave == 8) {
        // ---------------- producer: serial alpha chain --------------------
        const int c0 = 2 * lane;
        const float2 xv = *reinterpret_cast<const float2*>(vec + batch * SIZE + c0);
        float xa = xv.x, xb = xv.y;
        const bool hasR = (lane < 63);
        const bool hasL = (lane > 0);

        for (int grp = 0; grp < NG; ++grp) {
            float* buf = &alds[grp & 1][0];
#pragma unroll
            for (int j = 0; j < G; ++j) {
                // even layer: pair (2p, 2p+1), lane-local
                const float d  = xb - xa;
                const float ae = alpha_from_delta(d);
                buf[(2 * j) * 64 + lane] = ae;
                const float nxa0 = fmaf(-ae, d, xb);   // a' = b + ae*(a-b)
                const float nxb0 = fmaf( ae, d, xa);   // b' = a + ae*(b-a)
                // odd layer: pair (2p+1, 2p+2)
                const float xnext = dpp_mov<0x130>(nxa0);      // lane i <- i+1
                float ao = alpha_from_delta(xnext - nxb0);
                ao = hasR ? ao : 1.0f;                 // pad pair 63 -> identity
                buf[(2 * j + 1) * 64 + lane] = ao;
                float aoL = dpp_mov<0x138>(ao);        // lane i <- i-1
                aoL = hasL ? aoL : 1.0f;               // lane 0 -> identity
                const float xprev = dpp_mov<0x138>(nxb0);
                xb = fmaf(ao,  nxb0 - xnext, xnext);
                xa = fmaf(aoL, nxa0 - xprev, xprev);
            }
            __syncthreads();   // release group grp
        }
        if (rowgrp == 0)
            *reinterpret_cast<float2*>(out + batch * SIZE + c0) = make_float2(xa, xb);
    } else {
        // ---------------- consumers: evolve X rows ------------------------
        const int chunk   = lane & 15;          // cols 8*chunk .. 8*chunk+7
        const int row_sub = lane >> 4;
        const int row     = rowgrp * 32 + wave * 4 + row_sub;
        const int c8      = chunk * 8;
        const int q4      = chunk * 4;                       // even-pair base
        const int qm      = (chunk > 0) ? q4 - 1 : 63;       // left odd pair (63 = 1.0 pad)

        float v[8];
#pragma unroll
        for (int j = 0; j < 8; ++j) v[j] = (row == c8 + j) ? 1.0f : 0.0f;

        for (int grp = 0; grp < NG; ++grp) {
            __syncthreads();   // wait for group grp
            const float* buf = &alds[grp & 1][0];
            float4 ae = *reinterpret_cast<const float4*>(buf + q4);
            float4 ao = *reinterpret_cast<const float4*>(buf + 64 + q4);
            float  aL = buf[64 + qm];
#pragma unroll
            for (int j = 0; j < G; ++j) {
                const int nj = (j < G - 1) ? j + 1 : j;
                const float4 ae_n = *reinterpret_cast<const float4*>(buf + (2 * nj) * 64 + q4);
                const float4 ao_n = *reinterpret_cast<const float4*>(buf + (2 * nj + 1) * 64 + q4);
                const float  aL_n = buf[(2 * nj + 1) * 64 + qm];

                // even layer: pairs (v0,v1)(v2,v3)(v4,v5)(v6,v7)
                float A, B, d;
                A = v[0]; B = v[1]; d = A - B; v[0] = fmaf(ae.x, d, B); v[1] = fmaf(-ae.x, d, A);
                A = v[2]; B = v[3]; d = A - B; v[2] = fmaf(ae.y, d, B); v[3] = fmaf(-ae.y, d, A);
                A = v[4]; B = v[5]; d = A - B; v[4] = fmaf(ae.z, d, B); v[5] = fmaf(-ae.z, d, A);
                A = v[6]; B = v[7]; d = A - B; v[6] = fmaf(ae.w, d, B); v[7] = fmaf(-ae.w, d, A);
                // boundary values (post-even; lanes lockstep)
                const float nb0 = dpp_mov<0x101>(v[0]);   // right nbr col c8+8
                const float pb7 = dpp_mov<0x111>(v[7]);   // left nbr col c8-1
                // odd layer: internal pairs (v1,v2)(v3,v4)(v5,v6)
                A = v[1]; B = v[2]; d = A - B; v[1] = fmaf(ao.x, d, B); v[2] = fmaf(-ao.x, d, A);
                A = v[3]; B = v[4]; d = A - B; v[3] = fmaf(ao.y, d, B); v[4] = fmaf(-ao.y, d, A);
                A = v[5]; B = v[6]; d = A - B; v[5] = fmaf(ao.z, d, B); v[6] = fmaf(-ao.z, d, A);
                // boundary pairs; chunk edges get alpha==1.0 pad -> exact no-op
                v[7] = fmaf(ao.w, v[7] - nb0, nb0);
                v[0] = fmaf(aL,   v[0] - pb7, pb7);

                ae = ae_n; ao = ao_n; aL = aL_n;
            }
        }

        float* __restrict__ X = out + BATCH * SIZE + (batch * SIZE + row) * SIZE + c8;
        *reinterpret_cast<float4*>(X)     = make_float4(v[0], v[1], v[2], v[3]);
        *reinterpret_cast<float4*>(X + 4) = make_float4(v[4], v[5], v[6], v[7]);
    }
}

extern "C" void kernel_launch(void* const* d_in, const int* in_sizes, int n_in,
                              void* d_out, int out_size, void* d_ws, size_t ws_size,
                              hipStream_t stream) {
    const float* vec = (const float*)d_in[0];
    float* out = (float*)d_out;
    (void)in_sizes; (void)n_in; (void)d_ws; (void)ws_size; (void)out_size;

    hipLaunchKernelGGL(soft_sort_fused, dim3(BATCH * 4), dim3(576), 0, stream,
                       vec, out);
}